// Round 16
// baseline (272.569 us; speedup 1.0000x reference)
//
#include <hip/hip_runtime.h>
#include <hip/hip_bf16.h>
#include <cstdint>
#include <cstddef>

#define LL 1024
#define BB 4
#define EE 1024
#define HH 16
#define HD 64
#define NHEADS 64   // BB*HH

typedef __bf16 bf16x8 __attribute__((ext_vector_type(8)));
typedef float f32x4 __attribute__((ext_vector_type(4)));
typedef unsigned short u16;
typedef unsigned char u8;

__device__ __forceinline__ u16 f2b(float f) {
  union { float f; unsigned int i; } v; v.f = f;
  unsigned int r = v.i + 0x7FFFu + ((v.i >> 16) & 1u); // RTNE
  return (u16)(r >> 16);
}
// fp8 e4m3 byte 'sel' of dword -> float (cvt sel must be literal: shift instead)
__device__ __forceinline__ float fp8sel(unsigned int m4, int sel) {
  return __builtin_amdgcn_cvt_f32_fp8((int)(m4 >> (sel * 8)), 0);
}

// async global->LDS, 16B per lane. LDS dest must be wave-uniform base + lane*16.
__device__ __forceinline__ void gload16(const u16* g, u16* l) {
  __builtin_amdgcn_global_load_lds(
      (const __attribute__((address_space(1))) unsigned int*)(const void*)g,
      (__attribute__((address_space(3))) unsigned int*)(void*)l, 16, 0, 0);
}

// ---------------------------------------------------------------------------
// Convert kernel, R15: q/k/v conversions REMOVED (gemm_in now reads fp32
// directly and converts during staging). Remaining: wi/wo fp32->bf16 and
// emask2 = fp8(exp(mask)) in the permuted E2 layout.
// TOTAL = 786432 (wi float4) + 262144 (wo float4) + 1048576 (mask float4)
//       = 2097152 -> 8192 blocks of 256.
// ---------------------------------------------------------------------------
#define CVT_TOTAL 2097152
__global__ __launch_bounds__(256)
void cvt_all(const float* __restrict__ wi, const float* __restrict__ wo,
             const float* __restrict__ mask,
             u16* __restrict__ wib, u16* __restrict__ wob,
             unsigned int* __restrict__ emask) {
  int i = blockIdx.x * 256 + threadIdx.x;
  if (i >= CVT_TOTAL) return;
  if (i >= 1048576) {              // mask segment -> fp8 exp, permuted layout
    int off = i - 1048576;         // 0..1048575
    int l15 = off & 15, chunk = (off >> 4) & 15, bq = off >> 8;  // bq 0..4095
    const float* mrow = mask + (size_t)bq * 1024 + chunk * 64 + l15;
    float e0 = __expf(mrow[0]);
    float e1 = __expf(mrow[16]);
    float e2 = __expf(mrow[32]);
    float e3 = __expf(mrow[48]);
    int lo = __builtin_amdgcn_cvt_pk_fp8_f32(e0, e1, 0, false);
    int vv = __builtin_amdgcn_cvt_pk_fp8_f32(e2, e3, lo, true);
    emask[(size_t)(bq * 16 + chunk) * 16 + l15] = (unsigned int)vv;
    return;
  }
  const float* s; u16* d; int off;
  if (i < 786432) { s = wi; d = wib; off = i; }
  else            { s = wo; d = wob; off = i - 786432; }
  const float4 t = ((const float4*)s)[off];
  u16 o[4] = { f2b(t.x), f2b(t.y), f2b(t.z), f2b(t.w) };
  *(uint2*)&d[(size_t)off * 4] = *(const uint2*)o;
}

// ---------------------------------------------------------------------------
// In-proj BT-GEMM: C[M,N] = A[M,K] @ B[N,K]^T + bias.  128x128 tile, BK=32,
// 512 threads (8 waves x 32x64), tri-buffered, conflict-free granule swizzle.
// R15: A READ AS FP32 DIRECTLY from query/key/value (cvt fused into staging):
// per tile each thread loads 2x float4 (A granule, 8 fp32) to REGS and one
// B gload_lds; per iter: {vmcnt(0)+lgkmcnt(0); s_barrier; ds_write A tile
// it+1 (cvt to bf16, 16B store); issue tile it+2; compute(it)}. Buffer
// (it+1)%3 WAR-safe (last read 2 barriers ago); ds_writes drain via lgkmcnt
// at next loop-top before the barrier; B-gload depth ~1 compute phase.
// Saves cvt_all's 48MB read + 24MB write of q/k/v at the cost of A fetch
// 24->48MB in a non-BW-bound kernel.
// ---------------------------------------------------------------------------
__global__ __launch_bounds__(512, 6)
void gemm_in(const float* __restrict__ A0, const float* __restrict__ A1,
             const float* __restrict__ A2, const u16* __restrict__ Bw,
             const float* __restrict__ bias,
             u16* __restrict__ Oq, u16* __restrict__ Ok, u16* __restrict__ Ov) {
  const int tid  = threadIdx.x;
  const int lane = tid & 63;
  const int wave = tid >> 6;        // 0..7
  const int quad = lane >> 4;
  const int l15  = lane & 15;
  const int wm = wave >> 1, wn = wave & 1;   // wm 0..3 (32-row), wn 0..1 (64-col)
  const int row0 = blockIdx.x * 128;
  const int col0 = blockIdx.y * 128;

  const int sec = col0 >> 10;
  const float* A = (sec == 0) ? A0 : ((sec == 1) ? A1 : A2);

  __shared__ __align__(16) u16 lA[3][128][4][8];  // 24KB, [r][granule-slot][8]
  __shared__ __align__(16) u16 lB[3][128][4][8];  // 24KB

  f32x4 acc[2][4];
#pragma unroll
  for (int i = 0; i < 2; ++i)
#pragma unroll
    for (int j = 0; j < 4; ++j) { acc[i][j][0]=0.f; acc[i][j][1]=0.f; acc[i][j][2]=0.f; acc[i][j][3]=0.f; }

  const int sr_ = tid >> 2, sgs = tid & 3;
  const int sgg = sgs ^ ((sr_ >> 1) & 3);       // global granule held in slot sgs

  float4 a0, a1;                                 // A granule in regs (8 fp32)

  // issue tile loads: 2 fp32x4 A-loads to regs + 1 B gload_lds
  auto stage_load = [&](int k0, int sbuf) {
    const float* ap = A + (size_t)(row0 + sr_) * EE + (k0 + (sgg << 3));
    a0 = *(const float4*)ap;
    a1 = *(const float4*)(ap + 4);
    gload16(Bw + (size_t)(col0 + sr_) * EE + (k0 + (sgg << 3)), &lB[sbuf][0][0][0] + tid * 8);
  };
  // convert + 16B LDS store of the staged A granule
  auto stage_write = [&](int sbuf) {
    u16 o[8] = { f2b(a0.x), f2b(a0.y), f2b(a0.z), f2b(a0.w),
                 f2b(a1.x), f2b(a1.y), f2b(a1.z), f2b(a1.w) };
    *(uint4*)&lA[sbuf][sr_][sgs][0] = *(const uint4*)o;
  };

  auto compute = [&](int cbuf) {
    const int gslot = quad ^ ((l15 >> 1) & 3);  // slot holding granule 'quad'
    bf16x8 af[2], bfr[4];
#pragma unroll
    for (int i = 0; i < 2; ++i) af[i]  = *(const bf16x8*)&lA[cbuf][wm * 32 + i * 16 + l15][gslot][0];
#pragma unroll
    for (int j = 0; j < 4; ++j) bfr[j] = *(const bf16x8*)&lB[cbuf][wn * 64 + j * 16 + l15][gslot][0];
#pragma unroll
    for (int i = 0; i < 2; ++i)
#pragma unroll
      for (int j = 0; j < 4; ++j)
        acc[i][j] = __builtin_amdgcn_mfma_f32_16x16x32_bf16(af[i], bfr[j], acc[i][j], 0, 0, 0);
  };

  // prologue: tile0 staged+written, tile1 loads in flight
  stage_load(0, 0);
  asm volatile("s_waitcnt vmcnt(0)" ::: "memory");
  stage_write(0);
  stage_load(32, 1);

  for (int it = 0; it < 32; ++it) {
    asm volatile("s_waitcnt vmcnt(0) lgkmcnt(0)" ::: "memory");  // tile it+1 loads + my prev ds_writes
    __builtin_amdgcn_s_barrier();
    __builtin_amdgcn_sched_barrier(0);
    if (it < 31) stage_write((it + 1) % 3);
    if (it < 30) stage_load((it + 2) * 32, (it + 2) % 3);
    compute(it % 3);
  }

#pragma unroll
  for (int i = 0; i < 2; ++i) {
    const int grb = row0 + wm * 32 + i * 16 + quad * 4;
#pragma unroll
    for (int j = 0; j < 4; ++j) {
      const int gc = col0 + wn * 64 + j * 16 + l15;
      const float bv = bias[gc];
#pragma unroll
      for (int r = 0; r < 4; ++r) {
        float val = acc[i][j][r] + bv;
        const int gr = grb + r;
        const int l = gr >> 2, b = gr & 3;       // row = l*BB + b
        const int e = gc & 1023;
        const int h = e >> 6, d = e & 63;
        const int n = b * 16 + h;
        if (sec == 0)      Oq[((size_t)n * LL + l) * HD + d] = f2b(val * 0.125f); // Q pre-scaled
        else if (sec == 1) Ok[((size_t)n * LL + l) * HD + d] = f2b(val);
        else               Ov[((size_t)n * HD + d) * LL + l] = f2b(val);          // V transposed
      }
    }
  }
}

// ---------------------------------------------------------------------------
// Out-proj BT-GEMM. 64x64 tile, grid (64,16) = 1024 blocks = exact 4/CU
// (R14-verified: +2.8us total). Wave-tile 32x32 (2x2 waves); tri-buffer
// counted-vmcnt (2 VMEM/thread/tile -> vmcnt(2)); LDS 24KB.
// ---------------------------------------------------------------------------
__global__ __launch_bounds__(256, 4)
void gemm_out(const u16* __restrict__ A, const u16* __restrict__ Bw,
              const float* __restrict__ bias, float* __restrict__ Of) {
  const int tid  = threadIdx.x;
  const int lane = tid & 63;
  const int wave = tid >> 6;        // 0..3
  const int quad = lane >> 4;
  const int l15  = lane & 15;
  const int wm = wave >> 1, wn = wave & 1;   // 2x2 of 32x32
  const int row0 = blockIdx.x * 64;
  const int col0 = blockIdx.y * 64;

  __shared__ __align__(16) u16 lA[3][64][4][8];   // 12KB total
  __shared__ __align__(16) u16 lB[3][64][4][8];   // 12KB total

  f32x4 acc[2][2];
#pragma unroll
  for (int i = 0; i < 2; ++i)
#pragma unroll
    for (int j = 0; j < 2; ++j) { acc[i][j][0]=0.f; acc[i][j][1]=0.f; acc[i][j][2]=0.f; acc[i][j][3]=0.f; }

  auto stage = [&](int k0, int sbuf) {
    int r = tid >> 2, gs = tid & 3;
    int gg = gs ^ ((r >> 1) & 3);
    gload16(A  + (size_t)(row0 + r) * EE + (k0 + (gg << 3)), &lA[sbuf][0][0][0] + tid * 8);
    gload16(Bw + (size_t)(col0 + r) * EE + (k0 + (gg << 3)), &lB[sbuf][0][0][0] + tid * 8);
  };

  auto compute = [&](int cbuf) {
    const int gslot = quad ^ ((l15 >> 1) & 3);
    bf16x8 af[2], bfr[2];
#pragma unroll
    for (int i = 0; i < 2; ++i) af[i]  = *(const bf16x8*)&lA[cbuf][wm * 32 + i * 16 + l15][gslot][0];
#pragma unroll
    for (int j = 0; j < 2; ++j) bfr[j] = *(const bf16x8*)&lB[cbuf][wn * 32 + j * 16 + l15][gslot][0];
#pragma unroll
    for (int i = 0; i < 2; ++i)
#pragma unroll
      for (int j = 0; j < 2; ++j)
        acc[i][j] = __builtin_amdgcn_mfma_f32_16x16x32_bf16(af[i], bfr[j], acc[i][j], 0, 0, 0);
  };

  stage(0, 0);
  stage(32, 1);

  for (int it = 0; it < 31; ++it) {
    asm volatile("s_waitcnt vmcnt(2)" ::: "memory");   // tile it landed; it+1 in flight
    __builtin_amdgcn_s_barrier();
    __builtin_amdgcn_sched_barrier(0);
    if (it < 30) stage((it + 2) * 32, (it + 2) % 3);
    compute(it % 3);
  }
  asm volatile("s_waitcnt vmcnt(0)" ::: "memory");
  __builtin_amdgcn_s_barrier();
  __builtin_amdgcn_sched_barrier(0);
  compute(31 % 3);

#pragma unroll
  for (int i = 0; i < 2; ++i) {
    const int grb = row0 + wm * 32 + i * 16 + quad * 4;
#pragma unroll
    for (int j = 0; j < 2; ++j) {
      const int gc = col0 + wn * 32 + j * 16 + l15;
      const float bv = bias[gc];
#pragma unroll
      for (int r = 0; r < 4; ++r)
        Of[(size_t)(grb + r) * EE + gc] = acc[i][j][r] + bv;
    }
  }
}

// ---------------------------------------------------------------------------
// Fused flash attention, no-max softmax. q-tile 128, k-chunk 64.
// 512 threads (8 waves x 16 q-rows). K/V double-buffered, 1 barrier/chunk;
// Q fragments hoisted; lW wave-private. LDS 66KB -> 2 blocks/CU.
// emask2 dword load per r, decoded with 4 literal-sel cvt_f32_fp8.
// ---------------------------------------------------------------------------
__global__ __launch_bounds__(512, 4)
void attn_fused(const u16* __restrict__ Qh, const u16* __restrict__ Kh,
                const u16* __restrict__ Vt, const u8* __restrict__ emask,
                float* __restrict__ rsbuf, u16* __restrict__ O) {
  const int tid = threadIdx.x, lane = tid & 63, wave = tid >> 6;  // wave 0..7
  const int quad = lane >> 4, l15 = lane & 15;
  const int n = blockIdx.x;
  const int q0 = blockIdx.y * 128;
  const int b = n >> 4, h = n & 15;
  const int qw = wave * 16;            // wave's q-row base within the tile

  __shared__ __align__(16) u16 lQ[8][128][8];     // 16KB
  __shared__ __align__(16) u16 lK[2][8][64][8];   // 16KB (double-buffered)
  __shared__ __align__(16) u16 lV[2][8][64][8];   // 16KB  [buf][kgroup][d][8]
  __shared__ __align__(16) u16 lW[128][72];       // 18KB (row stride 144B)

  const u16* Qb = Qh + ((size_t)n * LL + q0) * HD;
  const u16* Kb = Kh + (size_t)n * LL * HD;
  const u16* Vb = Vt + (size_t)n * HD * LL;
  const unsigned int* em32 = (const unsigned int*)emask;

  // prologue: stage Q + k-chunk 0 into buffer 0
#pragma unroll
  for (int p = 0; p < 2; ++p) {
    int lc = p * 512 + tid;
    gload16(Qb + (lc & 127) * HD + ((lc >> 7) << 3), &lQ[0][0][0] + lc * 8);
  }
  gload16(Kb + (size_t)(tid & 63) * HD + ((tid >> 6) << 3), &lK[0][0][0][0] + tid * 8);
  gload16(Vb + (size_t)(tid & 63) * LL + ((tid >> 6) << 3),  &lV[0][0][0][0] + tid * 8);
  __syncthreads();

  // Q-hoist: fragments are loop-invariant (wave's 16 rows)
  bf16x8 aq0 = *(const bf16x8*)&lQ[quad][qw + l15][0];
  bf16x8 aq1 = *(const bf16x8*)&lQ[4 + quad][qw + l15][0];

  float sr[4] = {0.f,0.f,0.f,0.f};
  f32x4 ctx[4];
#pragma unroll
  for (int j = 0; j < 4; ++j) { ctx[j][0]=0.f; ctx[j][1]=0.f; ctx[j][2]=0.f; ctx[j][3]=0.f; }

  int buf = 0;
  for (int kc = 0; kc < 16; ++kc) {
    // prefetch chunk kc+1 into buf^1 (safe: all waves passed the previous
    // end-of-iteration barrier, so nobody still reads buf^1)
    if (kc < 15) {
      gload16(Kb + (size_t)((kc + 1) * 64 + (tid & 63)) * HD + ((tid >> 6) << 3),
              &lK[buf ^ 1][0][0][0] + tid * 8);
      gload16(Vb + (size_t)(tid & 63) * LL + (kc + 1) * 64 + ((tid >> 6) << 3),
              &lV[buf ^ 1][0][0][0] + tid * 8);
    }

    // QK^T for this wave's 16 q-rows
    f32x4 sc[4];
#pragma unroll
    for (int jk = 0; jk < 4; ++jk) {
      bf16x8 bk0 = *(const bf16x8*)&lK[buf][quad][jk * 16 + l15][0];
      bf16x8 bk1 = *(const bf16x8*)&lK[buf][4 + quad][jk * 16 + l15][0];
      f32x4 a; a[0]=0.f; a[1]=0.f; a[2]=0.f; a[3]=0.f;
      a = __builtin_amdgcn_mfma_f32_16x16x32_bf16(aq0, bk0, a, 0, 0, 0);
      a = __builtin_amdgcn_mfma_f32_16x16x32_bf16(aq1, bk1, a, 0, 0, 0);
      sc[jk] = a;
    }
#pragma unroll
    for (int r = 0; r < 4; ++r) {
      const int q = q0 + qw + quad * 4 + r;
      const unsigned int m4 = em32[(((size_t)b * 1024 + q) * 16 + kc) * 16 + l15];
      float md[4];
      md[0] = __builtin_amdgcn_cvt_f32_fp8((int)m4, 0);
      md[1] = __builtin_amdgcn_cvt_f32_fp8((int)m4, 1);
      md[2] = __builtin_amdgcn_cvt_f32_fp8((int)m4, 2);
      md[3] = __builtin_amdgcn_cvt_f32_fp8((int)m4, 3);
      float ss = 0.0f;
#pragma unroll
      for (int jk = 0; jk < 4; ++jk) {
        float w = md[jk] * __expf(sc[jk][r]);
        ss += w;
        lW[qw + quad * 4 + r][jk * 16 + l15] = f2b(w);
      }
      sr[r] += ss;
    }

    // lW rows are wave-private: intra-wave lgkmcnt ordering suffices, no barrier.
#pragma unroll
    for (int ks = 0; ks < 2; ++ks) {
      bf16x8 aw = *(const bf16x8*)&lW[qw + l15][ks * 32 + quad * 8];
#pragma unroll
      for (int j = 0; j < 4; ++j) {
        bf16x8 bv = *(const bf16x8*)&lV[buf][ks * 4 + quad][j * 16 + l15][0];
        ctx[j] = __builtin_amdgcn_mfma_f32_16x16x32_bf16(aw, bv, ctx[j], 0, 0, 0);
      }
    }

    __syncthreads();   // drains my prefetch (vmcnt0) + all waves done reading buf
    buf ^= 1;
  }

  float rs[4];
#pragma unroll
  for (int i = 0; i < 4; ++i) {
#pragma unroll
    for (int d = 1; d < 16; d <<= 1) sr[i] += __shfl_xor(sr[i], d);
    rs[i] = 1.0f / sr[i];
  }
#pragma unroll
  for (int j = 0; j < 4; ++j) {
    const int d = j * 16 + l15;
#pragma unroll
    for (int r = 0; r < 4; ++r) {
      const int l = q0 + qw + quad * 4 + r;
      O[((size_t)l * BB + b) * EE + h * 64 + d] = f2b(ctx[j][r] * rs[r]);
    }
  }
  if (l15 == 0) {
#pragma unroll
    for (int r = 0; r < 4; ++r) {
      const int q = q0 + qw + quad * 4 + r;
      rsbuf[n * LL + q] = rs[r];   // reciprocal: avg kernel multiplies
    }
  }
}

// ---------------------------------------------------------------------------
// avg_weights: recompute scores per head; w_h = emask * exp(sc) * rs_h.
// q-tile 64 x k-chunk 128 -> grid (8,16,4)=512 blocks (2/CU); double-buffered
// Q/K staging (1 barrier/head-iter). rs loaded (reciprocal), no divisions.
// emask2 dword loads; decode via fp8sel (shift + literal-sel cvt).
// ---------------------------------------------------------------------------
__global__ __launch_bounds__(256, 2)
void attn_avg(const u16* __restrict__ Qh, const u16* __restrict__ Kh,
              const u8* __restrict__ emask, const float* __restrict__ rsbuf,
              float* __restrict__ avgout) {
  const int tid = threadIdx.x, lane = tid & 63, wave = tid >> 6;
  const int quad = lane >> 4, l15 = lane & 15;
  const int kc = blockIdx.x;         // k-chunk (128)
  const int q0 = blockIdx.y * 64;    // q-tile (64)
  const int b = blockIdx.z;

  __shared__ __align__(16) u16 lQ[2][8][64][8];    // 16KB
  __shared__ __align__(16) u16 lK[2][8][128][8];   // 32KB

  float acc[8][4];
#pragma unroll
  for (int j = 0; j < 8; ++j)
#pragma unroll
    for (int r = 0; r < 4; ++r) acc[j][r] = 0.0f;

  const int qrb = q0 + wave * 16;
  const unsigned int* em32 = (const unsigned int*)emask;

  // stage head 0 into buffer 0
  {
    const int n0 = b * 16;
    const u16* Qb = Qh + ((size_t)n0 * LL + q0) * HD;
    const u16* Kb = Kh + ((size_t)n0 * LL + kc * 128) * HD;
#pragma unroll
    for (int p = 0; p < 2; ++p) {
      int lc = p * 256 + tid;
      gload16(Qb + (lc & 63) * HD + ((lc >> 6) << 3), &lQ[0][0][0][0] + lc * 8);
    }
#pragma unroll
    for (int p = 0; p < 4; ++p) {
      int lc = p * 256 + tid;
      gload16(Kb + (size_t)(lc & 127) * HD + ((lc >> 7) << 3), &lK[0][0][0][0] + lc * 8);
    }
  }

  for (int h = 0; h < 16; ++h) {
    const int buf = h & 1;
    __syncthreads();   // staging for h drained; reads of buf^1 (h-1) complete
    if (h < 15) {
      const int n1 = b * 16 + h + 1;
      const u16* Qb = Qh + ((size_t)n1 * LL + q0) * HD;
      const u16* Kb = Kh + ((size_t)n1 * LL + kc * 128) * HD;
#pragma unroll
      for (int p = 0; p < 2; ++p) {
        int lc = p * 256 + tid;
        gload16(Qb + (lc & 63) * HD + ((lc >> 6) << 3), &lQ[buf ^ 1][0][0][0] + lc * 8);
      }
#pragma unroll
      for (int p = 0; p < 4; ++p) {
        int lc = p * 256 + tid;
        gload16(Kb + (size_t)(lc & 127) * HD + ((lc >> 7) << 3), &lK[buf ^ 1][0][0][0] + lc * 8);
      }
    }

    const int n = b * 16 + h;
    float rs[4];
#pragma unroll
    for (int r = 0; r < 4; ++r) {
      const int q = qrb + quad * 4 + r;
      rs[r] = rsbuf[n * LL + q];
    }
    bf16x8 aq0 = *(const bf16x8*)&lQ[buf][quad][wave * 16 + l15][0];
    bf16x8 aq1 = *(const bf16x8*)&lQ[buf][4 + quad][wave * 16 + l15][0];
#pragma unroll
    for (int j = 0; j < 8; ++j) {
      bf16x8 bk0 = *(const bf16x8*)&lK[buf][quad][j * 16 + l15][0];
      bf16x8 bk1 = *(const bf16x8*)&lK[buf][4 + quad][j * 16 + l15][0];
      f32x4 a; a[0]=0.f; a[1]=0.f; a[2]=0.f; a[3]=0.f;
      a = __builtin_amdgcn_mfma_f32_16x16x32_bf16(aq0, bk0, a, 0, 0, 0);
      a = __builtin_amdgcn_mfma_f32_16x16x32_bf16(aq1, bk1, a, 0, 0, 0);
#pragma unroll
      for (int r = 0; r < 4; ++r) acc[j][r] += __expf(a[r]) * rs[r];
    }
  }
#pragma unroll
  for (int j = 0; j < 8; ++j) {
    const int chunk = (kc << 1) + (j >> 2);       // k>>6 for k = kc*128+j*16+l15
#pragma unroll
    for (int r = 0; r < 4; ++r) {
      const int q = qrb + quad * 4 + r;
      const int k = kc * 128 + j * 16 + l15;
      const unsigned int m4 = em32[(((size_t)b * 1024 + q) * 16 + chunk) * 16 + l15];
      const size_t idx = ((size_t)b << 20) + (size_t)q * LL + k;
      avgout[idx] = acc[j][r] * 0.0625f * fp8sel(m4, j & 3);
    }
  }
}

extern "C" void kernel_launch(void* const* d_in, const int* in_sizes, int n_in,
                              void* d_out, int out_size, void* d_ws, size_t ws_size,
                              hipStream_t stream) {
  const float* query = (const float*)d_in[0];
  const float* key   = (const float*)d_in[1];
  const float* value = (const float*)d_in[2];
  const float* mask  = (const float*)d_in[3];  // [4,1024,1024] fp32
  const float* win   = (const float*)d_in[4];  // [3072,1024]
  const float* bin   = (const float*)d_in[5];  // [3072] fp32, read directly
  const float* wout  = (const float*)d_in[6];  // [1024,1024]
  const float* bout  = (const float*)d_in[7];  // [1024] fp32, read directly
  float* out = (float*)d_out;                  // attn_output[4M] ++ avg_weights[4M], fp32

  // workspace layout (qb/kb/vb slots retained but unused after R15 fusion)
  u16* qb    = (u16*)d_ws;
  u16* kb    = qb + (size_t)LL * BB * EE;
  u16* vb    = kb + (size_t)LL * BB * EE;
  u16* winb  = vb + (size_t)LL * BB * EE;         // [3072,1024] bf16
  u16* woutb = winb + (size_t)3 * EE * EE;        // [1024,1024] bf16
  u16* Qh = woutb + (size_t)EE * EE;              // [64][1024][64] bf16, pre-scaled 1/8
  u16* Kh = Qh + (size_t)NHEADS * LL * HD;        // [64][1024][64]
  u16* Vt = Kh + (size_t)NHEADS * LL * HD;        // [64][64][1024] (transposed)
  u16* O  = Vt + (size_t)NHEADS * LL * HD;        // [4096][1024]
  float* rsbuf = (float*)(O + (size_t)LL * BB * EE);  // [64][1024] fp32 (1/s)
  u8* emask = (u8*)(rsbuf + NHEADS * LL);         // [4,1024,1024] fp8 exp(mask), permuted E2 layout

  dim3 blk(256);
  cvt_all<<<dim3((CVT_TOTAL + 255) / 256), blk, 0, stream>>>(
      win, wout, mask, winb, woutb, (unsigned int*)emask);
  gemm_in<<<dim3(32, 24), dim3(512), 0, stream>>>(query, key, value, winb, bin, Qh, Kh, Vt);
  attn_fused<<<dim3(64, 8), dim3(512), 0, stream>>>(Qh, Kh, Vt, emask, rsbuf, O);
  attn_avg<<<dim3(8, 16, 4), blk, 0, stream>>>(Qh, Kh, emask, rsbuf, out + (size_t)LL * BB * EE);
  gemm_out<<<dim3(64, 16), blk, 0, stream>>>(O, woutb, bout, out);
}

// Round 17
// 253.979 us; speedup vs baseline: 1.0732x; 1.0732x over previous
//
#include <hip/hip_runtime.h>
#include <hip/hip_bf16.h>
#include <cstdint>
#include <cstddef>

#define LL 1024
#define BB 4
#define EE 1024
#define HH 16
#define HD 64
#define NHEADS 64   // BB*HH

typedef __bf16 bf16x8 __attribute__((ext_vector_type(8)));
typedef float f32x4 __attribute__((ext_vector_type(4)));
typedef unsigned short u16;
typedef unsigned char u8;

__device__ __forceinline__ u16 f2b(float f) {
  union { float f; unsigned int i; } v; v.f = f;
  unsigned int r = v.i + 0x7FFFu + ((v.i >> 16) & 1u); // RTNE
  return (u16)(r >> 16);
}
// fp8 e4m3 byte 'sel' of dword -> float (cvt sel must be literal: shift instead)
__device__ __forceinline__ float fp8sel(unsigned int m4, int sel) {
  return __builtin_amdgcn_cvt_f32_fp8((int)(m4 >> (sel * 8)), 0);
}

// async global->LDS, 16B per lane. LDS dest must be wave-uniform base + lane*16.
__device__ __forceinline__ void gload16(const u16* g, u16* l) {
  __builtin_amdgcn_global_load_lds(
      (const __attribute__((address_space(1))) unsigned int*)(const void*)g,
      (__attribute__((address_space(3))) unsigned int*)(void*)l, 16, 0, 0);
}

// ---------------------------------------------------------------------------
// One fused convert kernel: fp32->bf16 for q/k/v/win/wout, and emask2 =
// fp8(exp(mask)) in the permuted E2 layout (R9): byte index
//   E2(b,q,k) = ((bq*16 + (k>>6))*16 + (k&15))*4 + ((k>>4)&3)
// R16: restored q/k/v conversion (R15's fusion into gemm_in regressed:
// per-iter vmcnt(0) collapsed the pipeline depth to 0 -> gemm_in 43->72us;
// reg-staging loses to gload_lds where linear LDS layouts work).
// ---------------------------------------------------------------------------
#define CVT_TOTAL 5242880
__global__ __launch_bounds__(256)
void cvt_all(const float* __restrict__ q, const float* __restrict__ k,
             const float* __restrict__ v, const float* __restrict__ wi,
             const float* __restrict__ wo, const float* __restrict__ mask,
             u16* __restrict__ qb, u16* __restrict__ kb, u16* __restrict__ vb,
             u16* __restrict__ wib, u16* __restrict__ wob,
             unsigned int* __restrict__ emask) {
  int i = blockIdx.x * 256 + threadIdx.x;
  if (i >= CVT_TOTAL) return;
  if (i >= 4194304) {              // mask segment -> fp8 exp, permuted layout
    int off = i - 4194304;         // 0..1048575
    int l15 = off & 15, chunk = (off >> 4) & 15, bq = off >> 8;  // bq 0..4095
    const float* mrow = mask + (size_t)bq * 1024 + chunk * 64 + l15;
    float e0 = __expf(mrow[0]);
    float e1 = __expf(mrow[16]);
    float e2 = __expf(mrow[32]);
    float e3 = __expf(mrow[48]);
    int lo = __builtin_amdgcn_cvt_pk_fp8_f32(e0, e1, 0, false);
    int vv = __builtin_amdgcn_cvt_pk_fp8_f32(e2, e3, lo, true);
    emask[(size_t)(bq * 16 + chunk) * 16 + l15] = (unsigned int)vv;
    return;
  }
  const float* s; u16* d; int off;
  if (i < 1048576)      { s = q;  d = qb;  off = i; }
  else if (i < 2097152) { s = k;  d = kb;  off = i - 1048576; }
  else if (i < 3145728) { s = v;  d = vb;  off = i - 2097152; }
  else if (i < 3932160) { s = wi; d = wib; off = i - 3145728; }
  else                  { s = wo; d = wob; off = i - 3932160; }
  const float4 t = ((const float4*)s)[off];
  u16 o[4] = { f2b(t.x), f2b(t.y), f2b(t.z), f2b(t.w) };
  *(uint2*)&d[(size_t)off * 4] = *(const uint2*)o;
}

// ---------------------------------------------------------------------------
// In-proj BT-GEMM: C[M,N] = A[M,K] @ B[N,K]^T + bias.  128x128 tile, BK=32,
// 512 threads (8 waves x 32x64), tri-buffered counted-vmcnt (vmcnt(2)),
// coalesced staging + conflict-free (r>>1)&3 granule swizzle, natural
// blockIdx mapping. R14-verified config: 43us, Occupancy 43%, conflicts 0.
// ---------------------------------------------------------------------------
__global__ __launch_bounds__(512, 6)
void gemm_in(const u16* __restrict__ A0, const u16* __restrict__ A1,
             const u16* __restrict__ A2, const u16* __restrict__ Bw,
             const float* __restrict__ bias,
             u16* __restrict__ Oq, u16* __restrict__ Ok, u16* __restrict__ Ov) {
  const int tid  = threadIdx.x;
  const int lane = tid & 63;
  const int wave = tid >> 6;        // 0..7
  const int quad = lane >> 4;
  const int l15  = lane & 15;
  const int wm = wave >> 1, wn = wave & 1;   // wm 0..3 (32-row), wn 0..1 (64-col)
  const int row0 = blockIdx.x * 128;
  const int col0 = blockIdx.y * 128;

  const int sec = col0 >> 10;
  const u16* A = (sec == 0) ? A0 : ((sec == 1) ? A1 : A2);

  __shared__ __align__(16) u16 lA[3][128][4][8];  // 24KB, [r][granule-slot][8]
  __shared__ __align__(16) u16 lB[3][128][4][8];  // 24KB

  f32x4 acc[2][4];
#pragma unroll
  for (int i = 0; i < 2; ++i)
#pragma unroll
    for (int j = 0; j < 4; ++j) { acc[i][j][0]=0.f; acc[i][j][1]=0.f; acc[i][j][2]=0.f; acc[i][j][3]=0.f; }

  // 2 VMEM insts per thread per tile (1xA + 1xB); 512 threads cover the
  // 128x32 tile (128 rows x 4 granules). Each 4-lane cluster reads one row's
  // contiguous 64B (granule permuted by XOR (r>>1)&3); LDS dest lane-linear.
  auto stage = [&](int k0, int sbuf) {
    int r = tid >> 2, gs = tid & 3;
    int gg = gs ^ ((r >> 1) & 3);      // global granule held in slot gs
    gload16(A  + (size_t)(row0 + r) * EE + (k0 + (gg << 3)), &lA[sbuf][0][0][0] + tid * 8);
    gload16(Bw + (size_t)(col0 + r) * EE + (k0 + (gg << 3)), &lB[sbuf][0][0][0] + tid * 8);
  };

  auto compute = [&](int cbuf) {
    const int gslot = quad ^ ((l15 >> 1) & 3);  // slot holding granule 'quad'
    bf16x8 af[2], bfr[4];
#pragma unroll
    for (int i = 0; i < 2; ++i) af[i]  = *(const bf16x8*)&lA[cbuf][wm * 32 + i * 16 + l15][gslot][0];
#pragma unroll
    for (int j = 0; j < 4; ++j) bfr[j] = *(const bf16x8*)&lB[cbuf][wn * 64 + j * 16 + l15][gslot][0];
#pragma unroll
    for (int i = 0; i < 2; ++i)
#pragma unroll
      for (int j = 0; j < 4; ++j)
        acc[i][j] = __builtin_amdgcn_mfma_f32_16x16x32_bf16(af[i], bfr[j], acc[i][j], 0, 0, 0);
  };

  // prologue: tiles 0 and 1 in flight (4 outstanding loads)
  stage(0, 0);
  stage(32, 1);

  // steady state: compute tile it, keep tile it+1 in flight, issue tile it+2
  for (int it = 0; it < 31; ++it) {
    asm volatile("s_waitcnt vmcnt(2)" ::: "memory");   // tile it landed; it+1 stays in flight
    __builtin_amdgcn_s_barrier();
    __builtin_amdgcn_sched_barrier(0);
    if (it < 30) stage((it + 2) * 32, (it + 2) % 3);
    compute(it % 3);
  }
  // last tile (31): nothing left in flight beyond it
  asm volatile("s_waitcnt vmcnt(0)" ::: "memory");
  __builtin_amdgcn_s_barrier();
  __builtin_amdgcn_sched_barrier(0);
  compute(31 % 3);

#pragma unroll
  for (int i = 0; i < 2; ++i) {
    const int grb = row0 + wm * 32 + i * 16 + quad * 4;
#pragma unroll
    for (int j = 0; j < 4; ++j) {
      const int gc = col0 + wn * 64 + j * 16 + l15;
      const float bv = bias[gc];
#pragma unroll
      for (int r = 0; r < 4; ++r) {
        float val = acc[i][j][r] + bv;
        const int gr = grb + r;
        const int l = gr >> 2, b = gr & 3;       // row = l*BB + b
        const int e = gc & 1023;
        const int h = e >> 6, d = e & 63;
        const int n = b * 16 + h;
        if (sec == 0)      Oq[((size_t)n * LL + l) * HD + d] = f2b(val * 0.125f); // Q pre-scaled
        else if (sec == 1) Ok[((size_t)n * LL + l) * HD + d] = f2b(val);
        else               Ov[((size_t)n * HD + d) * LL + l] = f2b(val);          // V transposed
      }
    }
  }
}

// ---------------------------------------------------------------------------
// Out-proj BT-GEMM. 64x64 tile, grid (64,16) = 1024 blocks = exact 4/CU
// (R14-verified: +2.8us total). Wave-tile 32x32 (2x2 waves); tri-buffer
// counted-vmcnt (2 VMEM/thread/tile -> vmcnt(2)); LDS 24KB.
// ---------------------------------------------------------------------------
__global__ __launch_bounds__(256, 4)
void gemm_out(const u16* __restrict__ A, const u16* __restrict__ Bw,
              const float* __restrict__ bias, float* __restrict__ Of) {
  const int tid  = threadIdx.x;
  const int lane = tid & 63;
  const int wave = tid >> 6;        // 0..3
  const int quad = lane >> 4;
  const int l15  = lane & 15;
  const int wm = wave >> 1, wn = wave & 1;   // 2x2 of 32x32
  const int row0 = blockIdx.x * 64;
  const int col0 = blockIdx.y * 64;

  __shared__ __align__(16) u16 lA[3][64][4][8];   // 12KB total
  __shared__ __align__(16) u16 lB[3][64][4][8];   // 12KB total

  f32x4 acc[2][2];
#pragma unroll
  for (int i = 0; i < 2; ++i)
#pragma unroll
    for (int j = 0; j < 2; ++j) { acc[i][j][0]=0.f; acc[i][j][1]=0.f; acc[i][j][2]=0.f; acc[i][j][3]=0.f; }

  auto stage = [&](int k0, int sbuf) {
    int r = tid >> 2, gs = tid & 3;
    int gg = gs ^ ((r >> 1) & 3);
    gload16(A  + (size_t)(row0 + r) * EE + (k0 + (gg << 3)), &lA[sbuf][0][0][0] + tid * 8);
    gload16(Bw + (size_t)(col0 + r) * EE + (k0 + (gg << 3)), &lB[sbuf][0][0][0] + tid * 8);
  };

  auto compute = [&](int cbuf) {
    const int gslot = quad ^ ((l15 >> 1) & 3);
    bf16x8 af[2], bfr[2];
#pragma unroll
    for (int i = 0; i < 2; ++i) af[i]  = *(const bf16x8*)&lA[cbuf][wm * 32 + i * 16 + l15][gslot][0];
#pragma unroll
    for (int j = 0; j < 2; ++j) bfr[j] = *(const bf16x8*)&lB[cbuf][wn * 32 + j * 16 + l15][gslot][0];
#pragma unroll
    for (int i = 0; i < 2; ++i)
#pragma unroll
      for (int j = 0; j < 2; ++j)
        acc[i][j] = __builtin_amdgcn_mfma_f32_16x16x32_bf16(af[i], bfr[j], acc[i][j], 0, 0, 0);
  };

  stage(0, 0);
  stage(32, 1);

  for (int it = 0; it < 31; ++it) {
    asm volatile("s_waitcnt vmcnt(2)" ::: "memory");   // tile it landed; it+1 in flight
    __builtin_amdgcn_s_barrier();
    __builtin_amdgcn_sched_barrier(0);
    if (it < 30) stage((it + 2) * 32, (it + 2) % 3);
    compute(it % 3);
  }
  asm volatile("s_waitcnt vmcnt(0)" ::: "memory");
  __builtin_amdgcn_s_barrier();
  __builtin_amdgcn_sched_barrier(0);
  compute(31 % 3);

#pragma unroll
  for (int i = 0; i < 2; ++i) {
    const int grb = row0 + wm * 32 + i * 16 + quad * 4;
#pragma unroll
    for (int j = 0; j < 2; ++j) {
      const int gc = col0 + wn * 32 + j * 16 + l15;
      const float bv = bias[gc];
#pragma unroll
      for (int r = 0; r < 4; ++r)
        Of[(size_t)(grb + r) * EE + gc] = acc[i][j][r] + bv;
    }
  }
}

// ---------------------------------------------------------------------------
// Fused flash attention, no-max softmax. q-tile 128, k-chunk 64.
// 512 threads (8 waves x 16 q-rows). K/V double-buffered, 1 barrier/chunk;
// Q fragments hoisted; lW wave-private. LDS 66KB -> 2 blocks/CU.
// emask2 dword load per r, decoded with 4 literal-sel cvt_f32_fp8.
// ---------------------------------------------------------------------------
__global__ __launch_bounds__(512, 4)
void attn_fused(const u16* __restrict__ Qh, const u16* __restrict__ Kh,
                const u16* __restrict__ Vt, const u8* __restrict__ emask,
                float* __restrict__ rsbuf, u16* __restrict__ O) {
  const int tid = threadIdx.x, lane = tid & 63, wave = tid >> 6;  // wave 0..7
  const int quad = lane >> 4, l15 = lane & 15;
  const int n = blockIdx.x;
  const int q0 = blockIdx.y * 128;
  const int b = n >> 4, h = n & 15;
  const int qw = wave * 16;            // wave's q-row base within the tile

  __shared__ __align__(16) u16 lQ[8][128][8];     // 16KB
  __shared__ __align__(16) u16 lK[2][8][64][8];   // 16KB (double-buffered)
  __shared__ __align__(16) u16 lV[2][8][64][8];   // 16KB  [buf][kgroup][d][8]
  __shared__ __align__(16) u16 lW[128][72];       // 18KB (row stride 144B)

  const u16* Qb = Qh + ((size_t)n * LL + q0) * HD;
  const u16* Kb = Kh + (size_t)n * LL * HD;
  const u16* Vb = Vt + (size_t)n * HD * LL;
  const unsigned int* em32 = (const unsigned int*)emask;

  // prologue: stage Q + k-chunk 0 into buffer 0
#pragma unroll
  for (int p = 0; p < 2; ++p) {
    int lc = p * 512 + tid;
    gload16(Qb + (lc & 127) * HD + ((lc >> 7) << 3), &lQ[0][0][0] + lc * 8);
  }
  gload16(Kb + (size_t)(tid & 63) * HD + ((tid >> 6) << 3), &lK[0][0][0][0] + tid * 8);
  gload16(Vb + (size_t)(tid & 63) * LL + ((tid >> 6) << 3),  &lV[0][0][0][0] + tid * 8);
  __syncthreads();

  // Q-hoist: fragments are loop-invariant (wave's 16 rows)
  bf16x8 aq0 = *(const bf16x8*)&lQ[quad][qw + l15][0];
  bf16x8 aq1 = *(const bf16x8*)&lQ[4 + quad][qw + l15][0];

  float sr[4] = {0.f,0.f,0.f,0.f};
  f32x4 ctx[4];
#pragma unroll
  for (int j = 0; j < 4; ++j) { ctx[j][0]=0.f; ctx[j][1]=0.f; ctx[j][2]=0.f; ctx[j][3]=0.f; }

  int buf = 0;
  for (int kc = 0; kc < 16; ++kc) {
    // prefetch chunk kc+1 into buf^1 (safe: all waves passed the previous
    // end-of-iteration barrier, so nobody still reads buf^1)
    if (kc < 15) {
      gload16(Kb + (size_t)((kc + 1) * 64 + (tid & 63)) * HD + ((tid >> 6) << 3),
              &lK[buf ^ 1][0][0][0] + tid * 8);
      gload16(Vb + (size_t)(tid & 63) * LL + (kc + 1) * 64 + ((tid >> 6) << 3),
              &lV[buf ^ 1][0][0][0] + tid * 8);
    }

    // QK^T for this wave's 16 q-rows
    f32x4 sc[4];
#pragma unroll
    for (int jk = 0; jk < 4; ++jk) {
      bf16x8 bk0 = *(const bf16x8*)&lK[buf][quad][jk * 16 + l15][0];
      bf16x8 bk1 = *(const bf16x8*)&lK[buf][4 + quad][jk * 16 + l15][0];
      f32x4 a; a[0]=0.f; a[1]=0.f; a[2]=0.f; a[3]=0.f;
      a = __builtin_amdgcn_mfma_f32_16x16x32_bf16(aq0, bk0, a, 0, 0, 0);
      a = __builtin_amdgcn_mfma_f32_16x16x32_bf16(aq1, bk1, a, 0, 0, 0);
      sc[jk] = a;
    }
#pragma unroll
    for (int r = 0; r < 4; ++r) {
      const int q = q0 + qw + quad * 4 + r;
      const unsigned int m4 = em32[(((size_t)b * 1024 + q) * 16 + kc) * 16 + l15];
      float md[4];
      md[0] = __builtin_amdgcn_cvt_f32_fp8((int)m4, 0);
      md[1] = __builtin_amdgcn_cvt_f32_fp8((int)m4, 1);
      md[2] = __builtin_amdgcn_cvt_f32_fp8((int)m4, 2);
      md[3] = __builtin_amdgcn_cvt_f32_fp8((int)m4, 3);
      float ss = 0.0f;
#pragma unroll
      for (int jk = 0; jk < 4; ++jk) {
        float w = md[jk] * __expf(sc[jk][r]);
        ss += w;
        lW[qw + quad * 4 + r][jk * 16 + l15] = f2b(w);
      }
      sr[r] += ss;
    }

    // lW rows are wave-private: intra-wave lgkmcnt ordering suffices, no barrier.
#pragma unroll
    for (int ks = 0; ks < 2; ++ks) {
      bf16x8 aw = *(const bf16x8*)&lW[qw + l15][ks * 32 + quad * 8];
#pragma unroll
      for (int j = 0; j < 4; ++j) {
        bf16x8 bv = *(const bf16x8*)&lV[buf][ks * 4 + quad][j * 16 + l15][0];
        ctx[j] = __builtin_amdgcn_mfma_f32_16x16x32_bf16(aw, bv, ctx[j], 0, 0, 0);
      }
    }

    __syncthreads();   // drains my prefetch (vmcnt0) + all waves done reading buf
    buf ^= 1;
  }

  float rs[4];
#pragma unroll
  for (int i = 0; i < 4; ++i) {
#pragma unroll
    for (int d = 1; d < 16; d <<= 1) sr[i] += __shfl_xor(sr[i], d);
    rs[i] = 1.0f / sr[i];
  }
#pragma unroll
  for (int j = 0; j < 4; ++j) {
    const int d = j * 16 + l15;
#pragma unroll
    for (int r = 0; r < 4; ++r) {
      const int l = q0 + qw + quad * 4 + r;
      O[((size_t)l * BB + b) * EE + h * 64 + d] = f2b(ctx[j][r] * rs[r]);
    }
  }
  if (l15 == 0) {
#pragma unroll
    for (int r = 0; r < 4; ++r) {
      const int q = q0 + qw + quad * 4 + r;
      rsbuf[n * LL + q] = rs[r];   // reciprocal: avg kernel multiplies
    }
  }
}

// ---------------------------------------------------------------------------
// avg_weights: recompute scores per head; w_h = emask * exp(sc) * rs_h.
// q-tile 64 x k-chunk 128 -> grid (8,16,4)=512 blocks (2/CU); double-buffered
// Q/K staging (1 barrier/head-iter). rs loaded (reciprocal), no divisions.
// emask2 dword loads; decode via fp8sel (shift + literal-sel cvt).
// ---------------------------------------------------------------------------
__global__ __launch_bounds__(256, 2)
void attn_avg(const u16* __restrict__ Qh, const u16* __restrict__ Kh,
              const u8* __restrict__ emask, const float* __restrict__ rsbuf,
              float* __restrict__ avgout) {
  const int tid = threadIdx.x, lane = tid & 63, wave = tid >> 6;
  const int quad = lane >> 4, l15 = lane & 15;
  const int kc = blockIdx.x;         // k-chunk (128)
  const int q0 = blockIdx.y * 64;    // q-tile (64)
  const int b = blockIdx.z;

  __shared__ __align__(16) u16 lQ[2][8][64][8];    // 16KB
  __shared__ __align__(16) u16 lK[2][8][128][8];   // 32KB

  float acc[8][4];
#pragma unroll
  for (int j = 0; j < 8; ++j)
#pragma unroll
    for (int r = 0; r < 4; ++r) acc[j][r] = 0.0f;

  const int qrb = q0 + wave * 16;
  const unsigned int* em32 = (const unsigned int*)emask;

  // stage head 0 into buffer 0
  {
    const int n0 = b * 16;
    const u16* Qb = Qh + ((size_t)n0 * LL + q0) * HD;
    const u16* Kb = Kh + ((size_t)n0 * LL + kc * 128) * HD;
#pragma unroll
    for (int p = 0; p < 2; ++p) {
      int lc = p * 256 + tid;
      gload16(Qb + (lc & 63) * HD + ((lc >> 6) << 3), &lQ[0][0][0][0] + lc * 8);
    }
#pragma unroll
    for (int p = 0; p < 4; ++p) {
      int lc = p * 256 + tid;
      gload16(Kb + (size_t)(lc & 127) * HD + ((lc >> 7) << 3), &lK[0][0][0][0] + lc * 8);
    }
  }

  for (int h = 0; h < 16; ++h) {
    const int buf = h & 1;
    __syncthreads();   // staging for h drained; reads of buf^1 (h-1) complete
    if (h < 15) {
      const int n1 = b * 16 + h + 1;
      const u16* Qb = Qh + ((size_t)n1 * LL + q0) * HD;
      const u16* Kb = Kh + ((size_t)n1 * LL + kc * 128) * HD;
#pragma unroll
      for (int p = 0; p < 2; ++p) {
        int lc = p * 256 + tid;
        gload16(Qb + (lc & 63) * HD + ((lc >> 6) << 3), &lQ[buf ^ 1][0][0][0] + lc * 8);
      }
#pragma unroll
      for (int p = 0; p < 4; ++p) {
        int lc = p * 256 + tid;
        gload16(Kb + (size_t)(lc & 127) * HD + ((lc >> 7) << 3), &lK[buf ^ 1][0][0][0] + lc * 8);
      }
    }

    const int n = b * 16 + h;
    float rs[4];
#pragma unroll
    for (int r = 0; r < 4; ++r) {
      const int q = qrb + quad * 4 + r;
      rs[r] = rsbuf[n * LL + q];
    }
    bf16x8 aq0 = *(const bf16x8*)&lQ[buf][quad][wave * 16 + l15][0];
    bf16x8 aq1 = *(const bf16x8*)&lQ[buf][4 + quad][wave * 16 + l15][0];
#pragma unroll
    for (int j = 0; j < 8; ++j) {
      bf16x8 bk0 = *(const bf16x8*)&lK[buf][quad][j * 16 + l15][0];
      bf16x8 bk1 = *(const bf16x8*)&lK[buf][4 + quad][j * 16 + l15][0];
      f32x4 a; a[0]=0.f; a[1]=0.f; a[2]=0.f; a[3]=0.f;
      a = __builtin_amdgcn_mfma_f32_16x16x32_bf16(aq0, bk0, a, 0, 0, 0);
      a = __builtin_amdgcn_mfma_f32_16x16x32_bf16(aq1, bk1, a, 0, 0, 0);
#pragma unroll
      for (int r = 0; r < 4; ++r) acc[j][r] += __expf(a[r]) * rs[r];
    }
  }
#pragma unroll
  for (int j = 0; j < 8; ++j) {
    const int chunk = (kc << 1) + (j >> 2);       // k>>6 for k = kc*128+j*16+l15
#pragma unroll
    for (int r = 0; r < 4; ++r) {
      const int q = qrb + quad * 4 + r;
      const int k = kc * 128 + j * 16 + l15;
      const unsigned int m4 = em32[(((size_t)b * 1024 + q) * 16 + chunk) * 16 + l15];
      const size_t idx = ((size_t)b << 20) + (size_t)q * LL + k;
      avgout[idx] = acc[j][r] * 0.0625f * fp8sel(m4, j & 3);
    }
  }
}

extern "C" void kernel_launch(void* const* d_in, const int* in_sizes, int n_in,
                              void* d_out, int out_size, void* d_ws, size_t ws_size,
                              hipStream_t stream) {
  const float* query = (const float*)d_in[0];
  const float* key   = (const float*)d_in[1];
  const float* value = (const float*)d_in[2];
  const float* mask  = (const float*)d_in[3];  // [4,1024,1024] fp32
  const float* win   = (const float*)d_in[4];  // [3072,1024]
  const float* bin   = (const float*)d_in[5];  // [3072] fp32, read directly
  const float* wout  = (const float*)d_in[6];  // [1024,1024]
  const float* bout  = (const float*)d_in[7];  // [1024] fp32, read directly
  float* out = (float*)d_out;                  // attn_output[4M] ++ avg_weights[4M], fp32

  // workspace layout (~68.5 MB)
  u16* qb    = (u16*)d_ws;                        // bf16 copies of inputs
  u16* kb    = qb + (size_t)LL * BB * EE;
  u16* vb    = kb + (size_t)LL * BB * EE;
  u16* winb  = vb + (size_t)LL * BB * EE;         // [3072,1024] bf16
  u16* woutb = winb + (size_t)3 * EE * EE;        // [1024,1024] bf16
  u16* Qh = woutb + (size_t)EE * EE;              // [64][1024][64] bf16, pre-scaled 1/8
  u16* Kh = Qh + (size_t)NHEADS * LL * HD;        // [64][1024][64]
  u16* Vt = Kh + (size_t)NHEADS * LL * HD;        // [64][64][1024] (transposed)
  u16* O  = Vt + (size_t)NHEADS * LL * HD;        // [4096][1024]
  float* rsbuf = (float*)(O + (size_t)LL * BB * EE);  // [64][1024] fp32 (1/s)
  u8* emask = (u8*)(rsbuf + NHEADS * LL);         // [4,1024,1024] fp8 exp(mask), permuted E2 layout

  dim3 blk(256);
  cvt_all<<<dim3((CVT_TOTAL + 255) / 256), blk, 0, stream>>>(
      query, key, value, win, wout, mask, qb, kb, vb, winb, woutb,
      (unsigned int*)emask);
  gemm_in<<<dim3(32, 24), dim3(512), 0, stream>>>(qb, kb, vb, winb, bin, Qh, Kh, Vt);
  attn_fused<<<dim3(64, 8), dim3(512), 0, stream>>>(Qh, Kh, Vt, emask, rsbuf, O);
  attn_avg<<<dim3(8, 16, 4), blk, 0, stream>>>(Qh, Kh, emask, rsbuf, out + (size_t)LL * BB * EE);
  gemm_out<<<dim3(64, 16), blk, 0, stream>>>(O, woutb, bout, out);
}